// Round 1
// baseline (39.582 us; speedup 1.0000x reference)
//
#include <hip/hip_runtime.h>

namespace {

constexpr int G    = 76;
constexpr int NA   = 3;
constexpr int NC   = 85;          // 5 + 80 channels per anchor
constexpr int GG   = G * G;       // 5776
constexpr int ROW  = NC * G;      // 6460 floats per (b,a,i) block
constexpr int ROWV = ROW / 4;     // 1615 float4s
constexpr int JV   = G / 4;       // 19 float4s per input row

__device__ __forceinline__ float sigmoidf(float v) {
    // 1/(1+e^-v) via v_exp_f32 + v_rcp_f32; rel err ~1e-5, far under threshold
    return __builtin_amdgcn_rcpf(1.0f + __expf(-v));
}

__global__ __launch_bounds__(256)
void yolo_decode(const float* __restrict__ x,
                 const float* __restrict__ anchors,
                 const int* __restrict__ img_dim,
                 float* __restrict__ out)
{
    __shared__ alignas(16) float lds[ROW];

    const int blk = blockIdx.x;
    const int i = blk % G;              // grid row
    const int a = (blk / G) % NA;       // anchor
    const int b = blk / (G * NA);       // batch

    const float stride_f = (float)(*img_dim) / (float)G;   // 608/76 = 8
    const float aw = anchors[2 * a + 0];                    // note: (anchor/stride)*stride cancels
    const float ah = anchors[2 * a + 1];

    const float* __restrict__ xin =
        x + (size_t)(b * (NA * NC) + a * NC) * GG + (size_t)i * G;

    const int tid = threadIdx.x;

    // Load + transform: coalesced float4 reads of 85 input rows (19 vec4 each),
    // scatter into LDS transposed as [j][c] (pitch 85).
    for (int k4 = tid; k4 < ROWV; k4 += 256) {
        const int c  = k4 / JV;
        const int j4 = k4 - c * JV;
        const float4 v = *reinterpret_cast<const float4*>(xin + (size_t)c * GG + j4 * 4);
        const float vv[4] = {v.x, v.y, v.z, v.w};
        #pragma unroll
        for (int e = 0; e < 4; ++e) {
            const int j = j4 * 4 + e;
            const float val = vv[e];
            float r;
            if (c == 0)      r = (sigmoidf(val) + (float)j) * stride_f; // bx*stride
            else if (c == 1) r = (sigmoidf(val) + (float)i) * stride_f; // by*stride
            else if (c == 2) r = __expf(val) * aw;                      // bw*stride
            else if (c == 3) r = __expf(val) * ah;                      // bh*stride
            else             r = sigmoidf(val);                        // conf + cls
            lds[j * NC + c] = r;
        }
    }
    __syncthreads();

    // Store: 6460 contiguous floats per block, base ≡ 0 mod 4 → float4 stores.
    float* __restrict__ outp =
        out + (size_t)(b * (NA * GG) + a * GG + i * G) * NC;
    const float4* __restrict__ l4  = reinterpret_cast<const float4*>(lds);
    float4* __restrict__       o4p = reinterpret_cast<float4*>(outp);
    for (int o4 = tid; o4 < ROWV; o4 += 256) {
        o4p[o4] = l4[o4];
    }
}

} // namespace

extern "C" void kernel_launch(void* const* d_in, const int* in_sizes, int n_in,
                              void* d_out, int out_size, void* d_ws, size_t ws_size,
                              hipStream_t stream) {
    const float* x       = (const float*)d_in[0];
    const float* anchors = (const float*)d_in[1];
    const int*   img_dim = (const int*)d_in[2];
    float* outp = (float*)d_out;

    const int B = in_sizes[0] / (NA * NC * GG);   // 16
    const int nblocks = B * NA * G;               // 3648
    yolo_decode<<<nblocks, 256, 0, stream>>>(x, anchors, img_dim, outp);
}

// Round 3
// 36.339 us; speedup vs baseline: 1.0892x; 1.0892x over previous
//
#include <hip/hip_runtime.h>

namespace {

typedef float f32x4 __attribute__((ext_vector_type(4)));

constexpr int G      = 76;
constexpr int NA     = 3;
constexpr int NC     = 85;             // 5 + 80 channels per anchor
constexpr int GG     = G * G;          // 5776
constexpr int RPB    = 2;              // grid-rows per block
constexpr int JV     = G / 4;          // 19 float4 per row per channel
constexpr int CH_V4  = RPB * JV;       // 38 float4 per channel chunk
constexpr int TOT_V4 = NC * CH_V4;     // 3230 float4 per block
constexpr int ROWF   = NC * G;         // 6460 floats per output row-slab
constexpr int LDSF   = RPB * ROWF;     // 12920 floats = 51,680 B
constexpr int NT     = 512;
constexpr int NIT    = (TOT_V4 + NT - 1) / NT;   // 7

__device__ __forceinline__ float sigmoidf(float v) {
    return __builtin_amdgcn_rcpf(1.0f + __expf(-v));
}

__global__ __launch_bounds__(NT)
void yolo_decode(const float* __restrict__ x,
                 const float* __restrict__ anchors,
                 const int* __restrict__ img_dim,
                 float* __restrict__ out)
{
    __shared__ alignas(16) float lds[LDSF];

    const int blk = blockIdx.x;
    const int ip  = blk % (G / RPB);            // 0..37
    const int a   = (blk / (G / RPB)) % NA;
    const int b   = blk / ((G / RPB) * NA);
    const int i0  = ip * RPB;

    const float stride_f = (float)(*img_dim) / (float)G;   // 8
    const float aw = anchors[2 * a + 0];   // (anchor/stride)*stride cancels
    const float ah = anchors[2 * a + 1];

    const float* __restrict__ xin =
        x + (size_t)(b * (NA * NC) + a * NC) * GG + (size_t)i0 * G;

    const int tid = threadIdx.x;

    // Phase A: issue ALL global loads first (max outstanding vmcnt).
    f32x4 v[NIT];
    #pragma unroll
    for (int it = 0; it < NIT; ++it) {
        const int k4 = it * NT + tid;
        if (it < NIT - 1 || k4 < TOT_V4) {
            const int c  = k4 / CH_V4;
            const int q  = k4 - c * CH_V4;      // 0..37, contiguous 608B chunk
            v[it] = *reinterpret_cast<const f32x4*>(
                xin + (size_t)c * GG + (size_t)q * 4);
        }
    }

    // Phase B: transform + transpose-scatter into LDS as [r][j][c].
    #pragma unroll
    for (int it = 0; it < NIT; ++it) {
        const int k4 = it * NT + tid;
        if (it < NIT - 1 || k4 < TOT_V4) {
            const int c  = k4 / CH_V4;
            const int q  = k4 - c * CH_V4;
            const int r  = q / JV;              // 0..1
            const int j4 = q - r * JV;          // 0..18
            float* __restrict__ lrow = lds + r * ROWF;
            const float fi = (float)(i0 + r);
            #pragma unroll
            for (int e = 0; e < 4; ++e) {
                const int j = j4 * 4 + e;
                const float val = v[it][e];
                float rr;
                if (c == 0)      rr = (sigmoidf(val) + (float)j) * stride_f;
                else if (c == 1) rr = (sigmoidf(val) + fi) * stride_f;
                else if (c == 2) rr = __expf(val) * aw;
                else if (c == 3) rr = __expf(val) * ah;
                else             rr = sigmoidf(val);
                lrow[j * NC + c] = rr;
            }
        }
    }
    __syncthreads();

    // Phase C: 51,680 contiguous bytes per block, nontemporal float4 stores.
    float* __restrict__ outp =
        out + (size_t)((b * NA + a) * GG + i0 * G) * NC;
    const f32x4* __restrict__ l4 = reinterpret_cast<const f32x4*>(lds);
    f32x4* __restrict__ o4p = reinterpret_cast<f32x4*>(outp);
    #pragma unroll
    for (int it = 0; it < NIT; ++it) {
        const int o4 = it * NT + tid;
        if (it < NIT - 1 || o4 < TOT_V4) {
            __builtin_nontemporal_store(l4[o4], o4p + o4);
        }
    }
}

} // namespace

extern "C" void kernel_launch(void* const* d_in, const int* in_sizes, int n_in,
                              void* d_out, int out_size, void* d_ws, size_t ws_size,
                              hipStream_t stream) {
    const float* x       = (const float*)d_in[0];
    const float* anchors = (const float*)d_in[1];
    const int*   img_dim = (const int*)d_in[2];
    float* outp = (float*)d_out;

    const int B = in_sizes[0] / (NA * NC * GG);       // 16
    const int nblocks = B * NA * (G / RPB);           // 1824
    yolo_decode<<<nblocks, NT, 0, stream>>>(x, anchors, img_dim, outp);
}